// Round 14
// baseline (1100.258 us; speedup 1.0000x reference)
//
#include <hip/hip_runtime.h>
#include <hip/hip_cooperative_groups.h>
namespace cg = cooperative_groups;

typedef unsigned short u16;
typedef __attribute__((ext_vector_type(8))) short bf16x8;   // 8 x bf16 (4 VGPRs)
typedef __attribute__((ext_vector_type(4))) float f32x4;

#define NLEV 5
#define CCH 256
#define KTOT 2304            // 9 taps * 256 ci
#define P_TOT 8525           // sum HW
#define PP_TOT 9165          // sum (H+2)*(W+2)
#define PLS (PP_TOT*64)      // activation plane stride (u16), 4 planes of 64 ci
#define HSTR 11776           // halo LDS plane stride (u16) = 23 slabs * 512
#define NBLK 296             // mega grid (74 ptiles x 2 mtiles x 2 br)

__constant__ int   c_HW[NLEV]     = {6400, 1600, 400, 100, 25};
__constant__ int   c_W[NLEV]      = {80, 40, 20, 10, 5};    // H == W (square)
__constant__ int   c_off[NLEV]    = {0, 6400, 8000, 8400, 8500};
__constant__ int   c_poff[NLEV]   = {0, 6724, 8488, 8972, 9116};
__constant__ int   c_tls[NLEV+1]  = {0, 50, 65, 71, 73, 74};  // 16x8 tile starts
__constant__ int   c_ntx[NLEV]    = {5, 3, 2, 1, 1};          // tiles across
__constant__ float c_stridef[NLEV]= {8.f, 16.f, 32.f, 64.f, 128.f};

__device__ __forceinline__ u16 f2bf(float f){
  union { float f; unsigned u; } v; v.f = f;
  unsigned r = v.u + 0x7fffu + ((v.u >> 16) & 1u);   // RNE
  return (u16)(r >> 16);
}

// async global->LDS: 64 lanes x 16B; HW writes lane i to ldsbase + i*16.
__device__ __forceinline__ void g2l16(const u16* g, u16* l, int lane){
#if defined(__has_builtin)
#if __has_builtin(__builtin_amdgcn_global_load_lds)
  __builtin_amdgcn_global_load_lds(
      (const __attribute__((address_space(1))) unsigned int*)g,
      (__attribute__((address_space(3))) unsigned int*)l, 16, 0, 0);
  return;
#endif
#endif
  *(uint4*)(l + lane*8) = *(const uint4*)g;  // fallback: sync copy
}

// s_waitcnt imm (gfx9: vm[3:0] bits3:0, vm[5:4] bits15:14, exp[6:4], lgkm[11:8])
#define WAIT_VM4   0x0F74   // vmcnt(4):  A(t) landed, A(t+1) in flight
#define WAIT_VM10  0x0F7A   // vmcnt(10): A(t) landed; halo batch(6)+A(t+1) fly
#define WAIT_VM0   0x0F70   // vmcnt(0)
#define WAIT_LGKM0 0xC07F   // lgkmcnt(0)

struct MegaParams {
  const u16 *XF;
  u16 *XC, *XB;
  const u16 *WRC, *WRB, *WHC, *WHB;
  float *YC, *YB, *ST;
  const float *cls_b, *box_b, *cls_gw, *cls_gb, *box_gw, *box_gb;
  const float *score_b, *pred_b, *iou_b, *scales;
  float *out;
};

// ---------------------------------------------------------------------------
// Cooperative mega-kernel (take 2): NO __restrict__ (XC/XB are both read and
// written within this function across grid.syncs — restrict here is UB), and
// explicit __threadfence() around each grid.sync for XCD coherence.
// Internals = R11 verbatim (wave-private A chains, 2-plane halo dbuf,
// 3 K-loop barriers). LDS 80,000 B -> 2 blocks/CU -> 296 blocks fit.
// ---------------------------------------------------------------------------
__global__ __launch_bounds__(256, 2) void fcos_mega(MegaParams P)
{
  __shared__ u16 hB[2*HSTR];        // 47104 B
  __shared__ u16 sA[4][2][2048];    // 32768 B
  __shared__ float sstat[16][2];
  cg::grid_group grid = cg::this_grid();

  const int bid = blockIdx.x;
  const int tid = threadIdx.x, wv = tid >> 6, ln = tid & 63;
  const int quad = ln >> 4, l15 = ln & 15;

  // ---- tower mapping ----
  const int ptile = bid % 74;
  const int mtile = (bid / 74) & 1;
  const int br    = bid / 148;
  int lv = 0;
  #pragma unroll
  for (int i = 1; i < NLEV; i++) if (ptile >= c_tls[i]) lv = i;
  const int tidx = ptile - c_tls[lv];
  const int ntx = c_ntx[lv];
  const int ty0 = (tidx / ntx) * 8, tx0 = (tidx - (tidx / ntx) * ntx) * 16;
  const int W = c_W[lv], wrow2 = W + 2;
  const int gx = tx0 + l15;
  const int aoff = (mtile*16 + wv*4)*512 + ln*8;

  // halo offsets (X-independent): slab j = wv+4i (j>22 -> idempotent dup)
  int hoff[6], hslab[6];
  #pragma unroll
  for (int i = 0; i < 6; i++) {
    int j = wv + 4*i;
    if (j > 22) j -= 4;
    hslab[i] = j;
    const int item = j*64 + ln;
    int hp = item >> 3; if (hp >= 180) hp -= 180;
    const int g = item & 7;
    const int hy = hp / 18, hx = hp - hy*18;
    const int prow = c_poff[lv] + (ty0 + hy)*wrow2 + tx0 + hx;
    hoff[i] = prow*64 + ((g ^ (hp & 7)) << 3);
  }

  // =================== layer loop ===================
  #pragma unroll 1
  for (int l = 0; l < 4; l++) {
    const u16* X = (l == 0) ? P.XF : (br ? (const u16*)P.XB : (const u16*)P.XC);
    const u16* WA = (br ? P.WRB : P.WRC) + (size_t)l*589824;
    const float* bias = (br ? P.box_b : P.cls_b) + l*256;
    float* Y = br ? P.YB : P.YC;
    float* STl = P.ST + (size_t)l*2*NLEV*32*2;

    auto stageH = [&](int plane) {
      u16* dst = &hB[(plane & 1) * HSTR];
      const size_t cof = (size_t)plane * PLS;
      #pragma unroll
      for (int i = 0; i < 6; i++)
        g2l16(X + hoff[i] + cof, dst + hslab[i]*512, ln);
    };
    auto stageA = [&](int s, int b) {
      const u16* as = WA + aoff + (size_t)s * 16384;
      u16* da = &sA[wv][b][0];
      #pragma unroll
      for (int j = 0; j < 4; j++) g2l16(as + j*512, da + j*512, ln);
    };

    f32x4 acc[2][8];
    #pragma unroll
    for (int i = 0; i < 2; i++)
      #pragma unroll
      for (int j = 0; j < 8; j++) acc[i][j] = (f32x4){0.f, 0.f, 0.f, 0.f};

    if (tid < 32) sstat[tid >> 1][tid & 1] = 0.f;

    // prologue: halo planes 0,1 + A stages t=0,1; one barrier
    stageH(0);
    stageH(1);
    stageA(0, 0);                              // t=0: tap0 cc0 -> s=0
    stageA(4, 1);                              // t=1: tap1 cc0 -> s=4
    __syncthreads();                           // drains vm; LDS visible

    // K-loop: t = cc*9 + tap, wave-private A chains, 3 barriers
    int cc = 0, tap = 0;
    #pragma unroll 1
    for (int t = 0; t < 36; t++) {
      if (t == 10 || t == 19) __builtin_amdgcn_s_waitcnt(WAIT_VM10);
      else if (t == 35)       __builtin_amdgcn_s_waitcnt(WAIT_VM0);
      else                    __builtin_amdgcn_s_waitcnt(WAIT_VM4);
      if (tap == 0 && cc > 0) {                // t = 9,18,27
        __builtin_amdgcn_sched_barrier(0);
        __builtin_amdgcn_s_barrier();
        __builtin_amdgcn_sched_barrier(0);
        if (cc < 3) stageH(cc + 1);
      }
      const u16* myA = &sA[wv][t & 1][0];
      const u16* hpl = &hB[(cc & 1) * HSTR];
      const int dh = tap / 3, dw = tap - dh*3;
      bf16x8 af[2][2], bf[2][8];
      #pragma unroll
      for (int sub = 0; sub < 2; sub++) {
        const int q = sub*4 + quad;
        const int swzA = (q ^ (l15 & 7)) * 8;
        #pragma unroll
        for (int mt = 0; mt < 2; mt++)
          af[sub][mt] = *(const bf16x8*)&myA[(mt*16 + l15)*64 + swzA];
        #pragma unroll
        for (int nt = 0; nt < 8; nt++) {
          const int hp = (nt + dh)*18 + l15 + dw;
          bf[sub][nt] = *(const bf16x8*)&hpl[hp*64 + ((q ^ (hp & 7)) << 3)];
        }
      }
      __builtin_amdgcn_s_waitcnt(WAIT_LGKM0);
      if (t < 34) {
        int tap2 = tap + 2, cc2 = cc;
        if (tap2 >= 9) { tap2 -= 9; cc2++; }
        stageA(tap2*4 + cc2, t & 1);
      }
      #pragma unroll
      for (int sub = 0; sub < 2; sub++)
        #pragma unroll
        for (int mt = 0; mt < 2; mt++)
          #pragma unroll
          for (int nt = 0; nt < 8; nt++)
            acc[mt][nt] = __builtin_amdgcn_mfma_f32_16x16x32_bf16(
                af[sub][mt], bf[sub][nt], acc[mt][nt], 0, 0, 0);
      if (++tap == 9) { tap = 0; cc++; }
    }

    // epilogue: Y (+bias) + fused GN stats
    #pragma unroll
    for (int mt = 0; mt < 2; mt++) {
      const int mloc = wv*32 + mt*16 + quad*4;
      const int mrow = mtile*128 + mloc;
      const f32x4 bv = *(const f32x4*)&bias[mrow];
      float s = 0.f, sq = 0.f;
      #pragma unroll
      for (int nt = 0; nt < 8; nt++) {
        const int gy = ty0 + nt;
        f32x4 v = acc[mt][nt] + bv;
        if (gy < W && gx < W) {
          const size_t n = (size_t)(c_off[lv] + gy*W + gx);
          *(f32x4*)&Y[n*CCH + mrow] = v;
          #pragma unroll
          for (int r = 0; r < 4; r++) { s += v[r]; sq += v[r]*v[r]; }
        }
      }
      #pragma unroll
      for (int o = 1; o < 16; o <<= 1) { s += __shfl_xor(s, o); sq += __shfl_xor(sq, o); }
      if (l15 == 0) {
        const int g = mloc >> 3;
        atomicAdd(&sstat[g][0], s);
        atomicAdd(&sstat[g][1], sq);
      }
    }
    __syncthreads();
    if (tid < 32) {
      const int g = tid >> 1, c = tid & 1;
      atomicAdd(&STl[((br*NLEV + lv)*32 + mtile*16 + g)*2 + c], sstat[g][c]);
    }

    __threadfence();
    grid.sync();   // stats + Y visible device-wide
    __threadfence();

    // ---- GN finalize + affine + ReLU -> planar X (grid-stride) ----
    for (int t0 = bid*256 + tid; t0 < 2*P_TOT*32; t0 += NBLK*256) {
      const int gbr = t0 / (P_TOT * 32);
      const int r  = t0 - gbr * (P_TOT * 32);
      const int pg = r >> 5;
      const int c0 = (r & 31) << 3;
      int glv = 0;
      #pragma unroll
      for (int i = 1; i < NLEV; i++) if (pg >= c_off[i]) glv = i;
      const int pl = pg - c_off[glv];
      const int Wl = c_W[glv];
      const int gg = c0 >> 3;
      const float* st = &STl[((gbr*NLEV + glv)*32 + gg)*2];
      const float cnt = 8.f * (float)c_HW[glv];
      const float mean = st[0] / cnt;
      const float var  = st[1] / cnt - mean*mean;
      const float rstd = rsqrtf(var + 1e-5f);
      const float* Yg = gbr ? P.YB : P.YC;
      const float* gw = (gbr ? P.box_gw : P.cls_gw) + l*256;
      const float* gb = (gbr ? P.box_gb : P.cls_gb) + l*256;
      u16* Xo = gbr ? P.XB : P.XC;
      const float* y = &Yg[(size_t)pg*CCH + c0];
      const int h = pl / Wl, wi = pl - h*Wl;
      const size_t pidx = (size_t)(c_poff[glv] + (h+1)*(Wl+2) + (wi+1));
      union { u16 u[8]; uint4 v; } pk;
      #pragma unroll
      for (int i = 0; i < 8; i++) {
        const float v = (y[i] - mean)*rstd*gw[c0+i] + gb[c0+i];
        pk.u[i] = f2bf(fmaxf(v, 0.f));
      }
      *(uint4*)&Xo[(size_t)(c0 >> 6)*PLS + pidx*64 + (c0 & 63)] = pk.v;
    }

    __threadfence();
    grid.sync();   // X visible for next layer
    __threadfence();
  }

  // =================== heads ===================
  if (bid >= 148) return;
  {
    const int hbr = bid / 74, hpt = bid % 74;
    int lv2 = 0;
    #pragma unroll
    for (int i = 1; i < NLEV; i++) if (hpt >= c_tls[i]) lv2 = i;
    const int tix = hpt - c_tls[lv2];
    const int nt2 = c_ntx[lv2];
    const int hy0 = (tix / nt2) * 8, hx0 = (tix - (tix / nt2) * nt2) * 16;
    const int W2 = c_W[lv2], wr2 = W2 + 2;
    const int gx2 = hx0 + l15;

    const u16* X = hbr ? (const u16*)P.XB : (const u16*)P.XC;
    const u16* WA = hbr ? P.WHB : P.WHC;
    const int aoff2 = (wv*4)*512 + ln*8;

    int hoff2[6], hslab2[6];
    #pragma unroll
    for (int i = 0; i < 6; i++) {
      int j = wv + 4*i;
      if (j > 22) j -= 4;
      hslab2[i] = j;
      const int item = j*64 + ln;
      int hp = item >> 3; if (hp >= 180) hp -= 180;
      const int g = item & 7;
      const int hy = hp / 18, hx = hp - hy*18;
      const int prow = c_poff[lv2] + (hy0 + hy)*wr2 + hx0 + hx;
      hoff2[i] = prow*64 + ((g ^ (hp & 7)) << 3);
    }

    auto stageH2 = [&](int plane) {
      u16* dst = &hB[(plane & 1) * HSTR];
      const size_t cof = (size_t)plane * PLS;
      #pragma unroll
      for (int i = 0; i < 6; i++)
        g2l16(X + hoff2[i] + cof, dst + hslab2[i]*512, ln);
    };
    auto stageA2 = [&](int s, int b) {
      const u16* as = WA + aoff2 + (size_t)s * 8192;
      u16* da = &sA[wv][b][0];
      #pragma unroll
      for (int j = 0; j < 4; j++) g2l16(as + j*512, da + j*512, ln);
    };

    f32x4 acc[2][8];
    #pragma unroll
    for (int i = 0; i < 2; i++)
      #pragma unroll
      for (int j = 0; j < 8; j++) acc[i][j] = (f32x4){0.f, 0.f, 0.f, 0.f};

    stageH2(0);
    stageH2(1);
    stageA2(0, 0);
    stageA2(4, 1);
    __syncthreads();

    int cc = 0, tap = 0;
    #pragma unroll 1
    for (int t = 0; t < 36; t++) {
      if (t == 10 || t == 19) __builtin_amdgcn_s_waitcnt(WAIT_VM10);
      else if (t == 35)       __builtin_amdgcn_s_waitcnt(WAIT_VM0);
      else                    __builtin_amdgcn_s_waitcnt(WAIT_VM4);
      if (tap == 0 && cc > 0) {
        __builtin_amdgcn_sched_barrier(0);
        __builtin_amdgcn_s_barrier();
        __builtin_amdgcn_sched_barrier(0);
        if (cc < 3) stageH2(cc + 1);
      }
      const u16* myA = &sA[wv][t & 1][0];
      const u16* hpl = &hB[(cc & 1) * HSTR];
      const int dh = tap / 3, dw = tap - dh*3;
      bf16x8 af[2][2], bf[2][8];
      #pragma unroll
      for (int sub = 0; sub < 2; sub++) {
        const int q = sub*4 + quad;
        const int swzA = (q ^ (l15 & 7)) * 8;
        #pragma unroll
        for (int mt = 0; mt < 2; mt++)
          af[sub][mt] = *(const bf16x8*)&myA[(mt*16 + l15)*64 + swzA];
        #pragma unroll
        for (int nt = 0; nt < 8; nt++) {
          const int hp = (nt + dh)*18 + l15 + dw;
          bf[sub][nt] = *(const bf16x8*)&hpl[hp*64 + ((q ^ (hp & 7)) << 3)];
        }
      }
      __builtin_amdgcn_s_waitcnt(WAIT_LGKM0);
      if (t < 34) {
        int tap2 = tap + 2, cc2 = cc;
        if (tap2 >= 9) { tap2 -= 9; cc2++; }
        stageA2(tap2*4 + cc2, t & 1);
      }
      #pragma unroll
      for (int sub = 0; sub < 2; sub++)
        #pragma unroll
        for (int mt = 0; mt < 2; mt++)
          #pragma unroll
          for (int nt = 0; nt < 8; nt++)
            acc[mt][nt] = __builtin_amdgcn_mfma_f32_16x16x32_bf16(
                af[sub][mt], bf[sub][nt], acc[mt][nt], 0, 0, 0);
      if (++tap == 9) { tap = 0; cc++; }
    }

    const float scl = P.scales[lv2];
    const float stf = c_stridef[lv2];
    #pragma unroll
    for (int mt = 0; mt < 2; mt++) {
      const int mr0 = wv*32 + mt*16 + quad*4;
      if (mr0 >= 85) continue;
      #pragma unroll
      for (int nt = 0; nt < 8; nt++) {
        const int gy = hy0 + nt;
        if (gy >= W2 || gx2 >= W2) continue;
        const size_t n = (size_t)(c_off[lv2] + gy*W2 + gx2);
        const f32x4 v = acc[mt][nt];
        #pragma unroll
        for (int r = 0; r < 4; r++) {
          const int m = mr0 + r;
          if (hbr == 0) {
            if (m < 80) P.out[n*85 + m] = v[r] + P.score_b[m];
          } else {
            if (m < 4) {
              const float t = (v[r] + P.pred_b[m]) * scl;      // Scale module
              P.out[n*85 + 80 + m] = fmaxf(t, 0.f) * stf;      // relu * stride
            } else if (m == 4) {
              P.out[n*85 + 84] = v[r] + P.iou_b[0];            // iou
            }
          }
        }
      }
    }
  }
}

// ======================= R11 fallback kernels (verbatim) =======================
template<int MODE>
__global__ __launch_bounds__(256, 2) void gemm_conv(
    const u16* __restrict__ Xc, const u16* __restrict__ Xb,
    const u16* __restrict__ Wc, const u16* __restrict__ Wb,
    const float* __restrict__ bc, const float* __restrict__ bb,
    float* __restrict__ Yc, float* __restrict__ Yb,
    float* __restrict__ stats,
    const float* __restrict__ predb, const float* __restrict__ ioub,
    const float* __restrict__ scales, float* __restrict__ out)
{
  __shared__ u16 hB[2*HSTR];
  __shared__ u16 sA[4][2][2048];
  __shared__ float sstat[16][2];

  const int ptile = blockIdx.x;
  const int mtile = (MODE == 0) ? blockIdx.y : 0;
  const int br = blockIdx.z;
  int lv = 0;
  #pragma unroll
  for (int i = 1; i < NLEV; i++) if (ptile >= c_tls[i]) lv = i;
  const int tidx = ptile - c_tls[lv];
  const int ntx = c_ntx[lv];
  const int ty0 = (tidx / ntx) * 8, tx0 = (tidx - (tidx / ntx) * ntx) * 16;
  const int W = c_W[lv], wrow2 = W + 2;

  const int tid = threadIdx.x, wv = tid >> 6, ln = tid & 63;
  const int quad = ln >> 4, l15 = ln & 15;

  const u16* __restrict__ X  = br ? Xb : Xc;
  const u16* __restrict__ WA = br ? Wb : Wc;

  const int ASTR = (MODE == 0) ? 16384 : 8192;
  const u16* abase = WA +
      (size_t)(((MODE == 0) ? mtile*16 : 0) + wv*4) * 512 + ln*8;

  const u16* hptr[6]; int hslab[6];
  #pragma unroll
  for (int i = 0; i < 6; i++) {
    int j = wv + 4*i;
    if (j > 22) j -= 4;
    hslab[i] = j;
    const int item = j*64 + ln;
    int hp = item >> 3; if (hp >= 180) hp -= 180;
    const int g = item & 7;
    const int hy = hp / 18, hx = hp - hy*18;
    const int prow = c_poff[lv] + (ty0 + hy)*wrow2 + tx0 + hx;
    hptr[i] = X + (size_t)prow*64 + ((g ^ (hp & 7)) << 3);
  }

  auto stageH = [&](int plane) {
    u16* dst = &hB[(plane & 1) * HSTR];
    const size_t cof = (size_t)plane * PLS;
    #pragma unroll
    for (int i = 0; i < 6; i++)
      g2l16(hptr[i] + cof, dst + hslab[i]*512, ln);
  };
  auto stageA = [&](int s, int b) {
    const u16* as = abase + (size_t)s * ASTR;
    u16* da = &sA[wv][b][0];
    #pragma unroll
    for (int j = 0; j < 4; j++) g2l16(as + j*512, da + j*512, ln);
  };

  f32x4 acc[2][8];
  #pragma unroll
  for (int i = 0; i < 2; i++)
    #pragma unroll
    for (int j = 0; j < 8; j++) acc[i][j] = (f32x4){0.f, 0.f, 0.f, 0.f};

  if (MODE == 0 && tid < 32) sstat[tid >> 1][tid & 1] = 0.f;

  stageH(0);
  stageH(1);
  stageA(0, 0);
  stageA(4, 1);
  __syncthreads();

  int cc = 0, tap = 0;
  #pragma unroll 1
  for (int t = 0; t < 36; t++) {
    if (t == 10 || t == 19) __builtin_amdgcn_s_waitcnt(WAIT_VM10);
    else if (t == 35)       __builtin_amdgcn_s_waitcnt(WAIT_VM0);
    else                    __builtin_amdgcn_s_waitcnt(WAIT_VM4);
    if (tap == 0 && cc > 0) {
      __builtin_amdgcn_sched_barrier(0);
      __builtin_amdgcn_s_barrier();
      __builtin_amdgcn_sched_barrier(0);
      if (cc < 3) stageH(cc + 1);
    }
    const u16* myA = &sA[wv][t & 1][0];
    const u16* hpl = &hB[(cc & 1) * HSTR];
    const int dh = tap / 3, dw = tap - dh*3;
    bf16x8 af[2][2], bf[2][8];
    #pragma unroll
    for (int sub = 0; sub < 2; sub++) {
      const int q = sub*4 + quad;
      const int swzA = (q ^ (l15 & 7)) * 8;
      #pragma unroll
      for (int mt = 0; mt < 2; mt++)
        af[sub][mt] = *(const bf16x8*)&myA[(mt*16 + l15)*64 + swzA];
      #pragma unroll
      for (int nt = 0; nt < 8; nt++) {
        const int hp = (nt + dh)*18 + l15 + dw;
        bf[sub][nt] = *(const bf16x8*)&hpl[hp*64 + ((q ^ (hp & 7)) << 3)];
      }
    }
    __builtin_amdgcn_s_waitcnt(WAIT_LGKM0);
    if (t < 34) {
      int tap2 = tap + 2, cc2 = cc;
      if (tap2 >= 9) { tap2 -= 9; cc2++; }
      stageA(tap2*4 + cc2, t & 1);
    }
    #pragma unroll
    for (int sub = 0; sub < 2; sub++)
      #pragma unroll
      for (int mt = 0; mt < 2; mt++)
        #pragma unroll
        for (int nt = 0; nt < 8; nt++)
          acc[mt][nt] = __builtin_amdgcn_mfma_f32_16x16x32_bf16(
              af[sub][mt], bf[sub][nt], acc[mt][nt], 0, 0, 0);
    if (++tap == 9) { tap = 0; cc++; }
  }

  const int gx = tx0 + l15;
  if (MODE == 0) {
    const float* __restrict__ bias = br ? bb : bc;
    float* __restrict__ Y = br ? Yb : Yc;
    #pragma unroll
    for (int mt = 0; mt < 2; mt++) {
      const int mloc = wv*32 + mt*16 + quad*4;
      const int mrow = mtile*128 + mloc;
      const f32x4 bv = *(const f32x4*)&bias[mrow];
      float s = 0.f, sq = 0.f;
      #pragma unroll
      for (int nt = 0; nt < 8; nt++) {
        const int gy = ty0 + nt;
        f32x4 v = acc[mt][nt] + bv;
        if (gy < W && gx < W) {
          const size_t n = (size_t)(c_off[lv] + gy*W + gx);
          *(f32x4*)&Y[n*CCH + mrow] = v;
          #pragma unroll
          for (int r = 0; r < 4; r++) { s += v[r]; sq += v[r]*v[r]; }
        }
      }
      #pragma unroll
      for (int o = 1; o < 16; o <<= 1) { s += __shfl_xor(s, o); sq += __shfl_xor(sq, o); }
      if (l15 == 0) {
        const int g = mloc >> 3;
        atomicAdd(&sstat[g][0], s);
        atomicAdd(&sstat[g][1], sq);
      }
    }
    __syncthreads();
    if (tid < 32) {
      const int g = tid >> 1, c = tid & 1;
      atomicAdd(&stats[((br*NLEV + lv)*32 + mtile*16 + g)*2 + c], sstat[g][c]);
    }
  } else {
    const float scl = scales[lv];
    const float stf = c_stridef[lv];
    #pragma unroll
    for (int mt = 0; mt < 2; mt++) {
      const int mr0 = wv*32 + mt*16 + quad*4;
      if (mr0 >= 85) continue;
      #pragma unroll
      for (int nt = 0; nt < 8; nt++) {
        const int gy = ty0 + nt;
        if (gy >= W || gx >= W) continue;
        const size_t n = (size_t)(c_off[lv] + gy*W + gx);
        const f32x4 v = acc[mt][nt];
        #pragma unroll
        for (int r = 0; r < 4; r++) {
          const int m = mr0 + r;
          if (br == 0) {
            if (m < 80) out[n*85 + m] = v[r] + bc[m];
          } else {
            if (m < 4) {
              const float t = (v[r] + predb[m]) * scl;
              out[n*85 + 80 + m] = fmaxf(t, 0.f) * stf;
            } else if (m == 4) {
              out[n*85 + 84] = v[r] + ioub[0];
            }
          }
        }
      }
    }
  }
}

__global__ __launch_bounds__(256) void gn_relu(
    const float* __restrict__ Yc, const float* __restrict__ Yb,
    const float* __restrict__ stats,
    const float* __restrict__ gwc, const float* __restrict__ gbc,
    const float* __restrict__ gwb, const float* __restrict__ gbb,
    u16* __restrict__ Xc, u16* __restrict__ Xb)
{
  const int t = blockIdx.x * 256 + threadIdx.x;
  if (t >= 2 * P_TOT * 32) return;
  const int br = t / (P_TOT * 32);
  const int r  = t - br * (P_TOT * 32);
  const int pg = r >> 5;
  const int c0 = (r & 31) << 3;
  int lv = 0;
  #pragma unroll
  for (int i = 1; i < NLEV; i++) if (pg >= c_off[i]) lv = i;
  const int pl = pg - c_off[lv];
  const int Wl = c_W[lv];
  const int g = c0 >> 3;
  const float* st = &stats[(((size_t)br*NLEV + lv)*32 + g)*2];
  const float cnt = 8.f * (float)c_HW[lv];
  const float mean = st[0] / cnt;
  const float var  = st[1] / cnt - mean*mean;
  const float rstd = rsqrtf(var + 1e-5f);
  const float* Y  = br ? Yb : Yc;
  const float* gw = br ? gwb : gwc;
  const float* gb = br ? gbb : gbc;
  u16* X = br ? Xb : Xc;
  const float* y = &Y[(size_t)pg*CCH + c0];
  const int h = pl / Wl, wi = pl - h*Wl;
  const size_t pidx = (size_t)(c_poff[lv] + (h+1)*(Wl+2) + (wi+1));
  union { u16 u[8]; uint4 v; } pk;
  #pragma unroll
  for (int i = 0; i < 8; i++) {
    const float v = (y[i] - mean)*rstd*gw[c0+i] + gb[c0+i];
    pk.u[i] = f2bf(fmaxf(v, 0.f));
  }
  *(uint4*)&X[(size_t)(c0 >> 6)*PLS + pidx*64 + (c0 & 63)] = pk.v;
}

// fp32 NCHW feats -> bf16 planar padded
__global__ __launch_bounds__(256) void feat2bf(
    const float* __restrict__ p3, const float* __restrict__ p4,
    const float* __restrict__ p5, const float* __restrict__ p6,
    const float* __restrict__ p7, u16* __restrict__ X)
{
  const int t = blockIdx.x * 256 + threadIdx.x;
  if (t >= P_TOT * 32) return;
  const int pg = t >> 5, c0 = (t & 31) << 3;
  int lv = 0;
  #pragma unroll
  for (int i = 1; i < NLEV; i++) if (pg >= c_off[i]) lv = i;
  const int pl = pg - c_off[lv];
  const float* src = lv==0 ? p3 : lv==1 ? p4 : lv==2 ? p5 : lv==3 ? p6 : p7;
  const int HW = c_HW[lv], Wl = c_W[lv];
  const int h = pl / Wl, wi = pl - h*Wl;
  const size_t pidx = (size_t)(c_poff[lv] + (h+1)*(Wl+2) + (wi+1));
  union { u16 u[8]; uint4 v; } pk;
  #pragma unroll
  for (int i = 0; i < 8; i++)
    pk.u[i] = f2bf(src[(size_t)(c0+i)*HW + pl]);
  *(uint4*)&X[(size_t)(c0 >> 6)*PLS + pidx*64 + (c0 & 63)] = pk.v;
}

// tower weights [l][co][ci][9] fp32 -> PACKED stage-major swizzled bf16 (R11)
__global__ __launch_bounds__(256) void wconv(
    const float* __restrict__ cw, const float* __restrict__ bw,
    u16* __restrict__ Wc, u16* __restrict__ Wb)
{
  const size_t N = (size_t)4*256*KTOT;
  const size_t t = (size_t)blockIdx.x * 256 + threadIdx.x;
  if (t >= 2*N) return;
  const float* src = (t < N) ? cw : bw;
  u16* dst = (t < N) ? Wc : Wb;
  const size_t i = (t < N) ? t : t - N;
  const size_t lc = i / KTOT;
  const int kk = (int)(i - lc*KTOT);
  const int l = (int)(lc >> 8), co = (int)(lc & 255);
  const int tap = kk >> 8, ci = kk & 255;
  const int s = kk >> 6, kl = kk & 63;
  const int r = co & 7, p = (kl >> 3) ^ r;
  const size_t d = (size_t)l*589824 +
      ((size_t)((s*32 + (co >> 3))*64 + r*8 + p))*8 + (kl & 7);
  dst[d] = f2bf(src[(lc*256 + ci)*9 + tap]);
}

// head weights -> packed 128-row swizzled (cls: 80 rows; box: 4 pred + 1 iou)
__global__ __launch_bounds__(256) void hconv(
    const float* __restrict__ sw, const float* __restrict__ pw,
    const float* __restrict__ iw, u16* __restrict__ Whc, u16* __restrict__ Whb)
{
  const int N = 128 * KTOT;
  const int t = blockIdx.x * 256 + threadIdx.x;
  if (t >= 2*N) return;
  const int i = (t < N) ? t : t - N;
  const int co = i / KTOT, kk = i - co*KTOT;
  const int tap = kk >> 8, ci = kk & 255;
  const int s = kk >> 6, kl = kk & 63;
  const int r = co & 7, p = (kl >> 3) ^ r;
  const size_t d = ((size_t)((s*16 + (co >> 3))*64 + r*8 + p))*8 + (kl & 7);
  float v = 0.f;
  if (t < N) {
    if (co < 80) v = sw[(co*256 + ci)*9 + tap];
    Whc[d] = f2bf(v);
  } else {
    if (co < 4)       v = pw[(co*256 + ci)*9 + tap];
    else if (co == 4) v = iw[ci*9 + tap];
    Whb[d] = f2bf(v);
  }
}

extern "C" void kernel_launch(void* const* d_in, const int* in_sizes, int n_in,
                              void* d_out, int out_size, void* d_ws, size_t ws_size,
                              hipStream_t stream)
{
  const float* p3      = (const float*)d_in[0];
  const float* p4      = (const float*)d_in[1];
  const float* p5      = (const float*)d_in[2];
  const float* p6      = (const float*)d_in[3];
  const float* p7      = (const float*)d_in[4];
  const float* cls_w   = (const float*)d_in[5];
  const float* cls_b   = (const float*)d_in[6];
  const float* cls_gw  = (const float*)d_in[7];
  const float* cls_gb  = (const float*)d_in[8];
  const float* box_w   = (const float*)d_in[9];
  const float* box_b   = (const float*)d_in[10];
  const float* box_gw  = (const float*)d_in[11];
  const float* box_gb  = (const float*)d_in[12];
  const float* score_w = (const float*)d_in[13];
  const float* score_b = (const float*)d_in[14];
  const float* pred_w  = (const float*)d_in[15];
  const float* pred_b  = (const float*)d_in[16];
  const float* iou_w   = (const float*)d_in[17];
  const float* iou_b   = (const float*)d_in[18];
  const float* scales  = (const float*)d_in[19];
  float* out = (float*)d_out;

  char* w = (char*)d_ws;
  size_t o = 0;
  auto alloc = [&](size_t b) { void* p = w + o; o += (b + 255) & ~(size_t)255; return p; };
  u16*   XF = (u16*)alloc((size_t)PP_TOT*CCH*2);   // planar [4][PP_TOT][64]
  u16*   XC = (u16*)alloc((size_t)PP_TOT*CCH*2);
  u16*   XB = (u16*)alloc((size_t)PP_TOT*CCH*2);
  float* ST = (float*)alloc((size_t)4*2*NLEV*32*2*4);   // [layer][br][lv][32][2]
  u16*  WRC = (u16*)alloc((size_t)4*256*KTOT*2);
  u16*  WRB = (u16*)alloc((size_t)4*256*KTOT*2);
  u16*  WHC = (u16*)alloc((size_t)128*KTOT*2);
  u16*  WHB = (u16*)alloc((size_t)128*KTOT*2);
  float* YC = (float*)alloc((size_t)P_TOT*CCH*4);
  float* YB = (float*)alloc((size_t)P_TOT*CCH*4);

  hipMemsetAsync(XF, 0, (size_t)3*PP_TOT*CCH*2 + (size_t)4*2*NLEV*32*2*4, stream);

  wconv<<<dim3((unsigned)(((size_t)2*4*256*KTOT + 255)/256)), 256, 0, stream>>>(cls_w, box_w, WRC, WRB);
  hconv<<<dim3((2*128*KTOT + 255)/256), 256, 0, stream>>>(score_w, pred_w, iou_w, WHC, WHB);
  feat2bf<<<dim3((P_TOT*32 + 255)/256), 256, 0, stream>>>(p3, p4, p5, p6, p7, XF);

  MegaParams mp;
  mp.XF = XF; mp.XC = XC; mp.XB = XB;
  mp.WRC = WRC; mp.WRB = WRB; mp.WHC = WHC; mp.WHB = WHB;
  mp.YC = YC; mp.YB = YB; mp.ST = ST;
  mp.cls_b = cls_b; mp.box_b = box_b;
  mp.cls_gw = cls_gw; mp.cls_gb = cls_gb;
  mp.box_gw = box_gw; mp.box_gb = box_gb;
  mp.score_b = score_b; mp.pred_b = pred_b; mp.iou_b = iou_b;
  mp.scales = scales; mp.out = out;
  void* kargs[] = { &mp };
  hipError_t ce = hipLaunchCooperativeKernel((const void*)fcos_mega, dim3(NBLK),
                                             dim3(256), kargs, 0, stream);
  if (ce != hipSuccess) {
    (void)hipGetLastError();   // clear sticky error; fall back to R11 path
    const u16* xci = XF; const u16* xbi = XF;
    for (int l = 0; l < 4; l++) {
      float* STl = ST + (size_t)l*2*NLEV*32*2;
      gemm_conv<0><<<dim3(74, 2, 2), 256, 0, stream>>>(
          xci, xbi, WRC + (size_t)l*589824, WRB + (size_t)l*589824,
          cls_b + l*256, box_b + l*256, YC, YB, STl,
          nullptr, nullptr, nullptr, nullptr);
      gn_relu<<<dim3((2*P_TOT*32 + 255)/256), 256, 0, stream>>>(
          YC, YB, STl, cls_gw + l*256, cls_gb + l*256, box_gw + l*256, box_gb + l*256,
          XC, XB);
      xci = XC; xbi = XB;
    }
    gemm_conv<1><<<dim3(74, 1, 2), 256, 0, stream>>>(
        xci, xbi, WHC, WHB, score_b, nullptr, nullptr, nullptr, nullptr,
        pred_b, iou_b, scales, out);
  }
}

// Round 15
// 373.161 us; speedup vs baseline: 2.9485x; 2.9485x over previous
//
#include <hip/hip_runtime.h>

typedef unsigned short u16;
typedef __attribute__((ext_vector_type(8))) short bf16x8;   // 8 x bf16 (4 VGPRs)
typedef __attribute__((ext_vector_type(4))) float f32x4;

#define NLEV 5
#define CCH 256
#define KTOT 2304            // 9 taps * 256 ci
#define P_TOT 8525           // sum HW
#define PP_TOT 9165          // sum (H+2)*(W+2)
#define PLS (PP_TOT*64)      // bf16 planar activation plane stride (u16)
#define HSTR 11776           // halo LDS plane stride (u16) = 23 slabs * 512

__constant__ int   c_HW[NLEV]     = {6400, 1600, 400, 100, 25};
__constant__ int   c_W[NLEV]      = {80, 40, 20, 10, 5};    // H == W (square)
__constant__ int   c_off[NLEV]    = {0, 6400, 8000, 8400, 8500};
__constant__ int   c_poff[NLEV]   = {0, 6724, 8488, 8972, 9116};
__constant__ int   c_tls[NLEV+1]  = {0, 50, 65, 71, 73, 74};  // 16x8 tile starts
__constant__ int   c_ntx[NLEV]    = {5, 3, 2, 1, 1};          // tiles across
__constant__ float c_stridef[NLEV]= {8.f, 16.f, 32.f, 64.f, 128.f};

__device__ __forceinline__ u16 f2bf(float f){
  union { float f; unsigned u; } v; v.f = f;
  unsigned r = v.u + 0x7fffu + ((v.u >> 16) & 1u);   // RNE
  return (u16)(r >> 16);
}

// async global->LDS: 64 lanes x 16B; HW writes lane i to ldsbase + i*16.
__device__ __forceinline__ void g2l16(const u16* g, u16* l, int lane){
#if defined(__has_builtin)
#if __has_builtin(__builtin_amdgcn_global_load_lds)
  __builtin_amdgcn_global_load_lds(
      (const __attribute__((address_space(1))) unsigned int*)g,
      (__attribute__((address_space(3))) unsigned int*)l, 16, 0, 0);
  return;
#endif
#endif
  *(uint4*)(l + lane*8) = *(const uint4*)g;  // fallback: sync copy
}

// s_waitcnt imm (gfx9: vm[3:0] bits3:0, vm[5:4] bits15:14, exp[6:4], lgkm[11:8])
#define WAIT_VM4   0x0F74   // vmcnt(4):  A(t) landed, A(t+1) in flight
#define WAIT_VM10  0x0F7A   // vmcnt(10): A(t) landed; halo batch(6)+A(t+1) fly
#define WAIT_VM0   0x0F70   // vmcnt(0)
#define WAIT_LGKM0 0xC07F   // lgkmcnt(0)

// ---------------------------------------------------------------------------
// R11 wave-chain halo implicit-GEMM conv 3x3, with GN FOLDED INTO STAGING.
// SRC==0 (layer 0): halo staged from bf16 planar XF via global_load_lds
//   (R11's exact path + vmcnt schedule with VM10 at t=10,19).
// SRC==1 (layers 1..3, heads): halo staged from previous layer's fp32 Y via
//   register loads, normalize relu(y*scale+shift) (per-channel coefs from
//   gn_coef), bf16 pack, ds_write_b128 into the SAME LDS halo layout.
//   OOB halo lanes write true zeros. cc-boundaries use __syncthreads().
// A chain, MFMA loop, epilogue (Y+bias write + fused GN stats) = R11 verbatim.
// MODE 0: towers, grid (74,2,2). MODE 1: heads, grid (74,1,2).
// ---------------------------------------------------------------------------
template<int MODE, int SRC>
__global__ __launch_bounds__(256, 2) void gemm_conv(
    const u16* __restrict__ Xc, const u16* __restrict__ Xb,       // SRC0 bf16
    const float* __restrict__ Ypc, const float* __restrict__ Ypb, // SRC1 fp32
    const float* __restrict__ CFS, const float* __restrict__ CFH, // SRC1 coefs
    const u16* __restrict__ Wc, const u16* __restrict__ Wb,
    const float* __restrict__ bc, const float* __restrict__ bb,
    float* __restrict__ Yc, float* __restrict__ Yb,
    float* __restrict__ stats,
    const float* __restrict__ predb, const float* __restrict__ ioub,
    const float* __restrict__ scales, float* __restrict__ out)
{
  __shared__ u16 hB[2*HSTR];        // 47104 B: halo plane dbuf
  __shared__ u16 sA[4][2][2048];    // 32768 B: per-wave A dbuf
  __shared__ float sstat[16][2];

  const int ptile = blockIdx.x;
  const int mtile = (MODE == 0) ? blockIdx.y : 0;
  const int br = blockIdx.z;
  int lv = 0;
  #pragma unroll
  for (int i = 1; i < NLEV; i++) if (ptile >= c_tls[i]) lv = i;
  const int tidx = ptile - c_tls[lv];
  const int ntx = c_ntx[lv];
  const int ty0 = (tidx / ntx) * 8, tx0 = (tidx - (tidx / ntx) * ntx) * 16;
  const int W = c_W[lv], wrow2 = W + 2;

  const int tid = threadIdx.x, wv = tid >> 6, ln = tid & 63;
  const int quad = ln >> 4, l15 = ln & 15;

  const u16* X = br ? Xb : Xc;                 // SRC0 planar bf16
  const float* Yp = br ? Ypb : Ypc;            // SRC1 fp32 prev-layer Y
  const u16* __restrict__ WA = br ? Wb : Wc;   // packed weights

  const int ASTR = (MODE == 0) ? 16384 : 8192;
  const u16* abase = WA +
      (size_t)(((MODE == 0) ? mtile*16 : 0) + wv*4) * 512 + ln*8;

  // Halo per-lane geometry: slab j = wv+4i (j>22 -> idempotent dup).
  const u16* hptr[6];   // SRC0
  int noffs[6], cfo[6]; bool oobf[6];          // SRC1
  int hslab[6];
  #pragma unroll
  for (int i = 0; i < 6; i++) {
    int j = wv + 4*i;
    if (j > 22) j -= 4;
    hslab[i] = j;
    const int item = j*64 + ln;
    int hp = item >> 3; if (hp >= 180) hp -= 180;
    const int g = item & 7;
    const int gsw8 = (g ^ (hp & 7)) * 8;
    const int hy = hp / 18, hx = hp - hy*18;
    if (SRC == 0) {
      const int prow = c_poff[lv] + (ty0 + hy)*wrow2 + tx0 + hx;
      hptr[i] = X + (size_t)prow*64 + gsw8;
    } else {
      const int y = ty0 + hy - 1, x = tx0 + hx - 1;
      oobf[i] = (y < 0) | (y >= W) | (x < 0) | (x >= W);
      const int n = oobf[i] ? 0 : (c_off[lv] + y*W + x);
      noffs[i] = n*256 + gsw8;
      cfo[i]   = (br*NLEV + lv)*256 + gsw8;
    }
  }

  uint4 hreg[6];                               // SRC1 staged bf16 halo regs
  auto stageH = [&](int plane) {               // SRC0: async DMA
    u16* dst = &hB[(plane & 1) * HSTR];
    const size_t cof = (size_t)plane * PLS;
    #pragma unroll
    for (int i = 0; i < 6; i++)
      g2l16(hptr[i] + cof, dst + hslab[i]*512, ln);
  };
  auto hloadN = [&](int cc) {                  // SRC1: load + normalize
    #pragma unroll
    for (int i = 0; i < 6; i++) {
      if (oobf[i]) { hreg[i] = (uint4){0,0,0,0}; continue; }
      const float* p = Yp + noffs[i] + cc*64;
      const f32x4 a0 = *(const f32x4*)p;
      const f32x4 a1 = *(const f32x4*)(p + 4);
      const float* cs = CFS + cfo[i] + cc*64;
      const float* ch = CFH + cfo[i] + cc*64;
      const f32x4 s0 = *(const f32x4*)cs, s1 = *(const f32x4*)(cs + 4);
      const f32x4 h0 = *(const f32x4*)ch, h1 = *(const f32x4*)(ch + 4);
      union { u16 u[8]; uint4 v; } pk;
      #pragma unroll
      for (int r = 0; r < 4; r++) pk.u[r]     = f2bf(fmaxf(a0[r]*s0[r] + h0[r], 0.f));
      #pragma unroll
      for (int r = 0; r < 4; r++) pk.u[4 + r] = f2bf(fmaxf(a1[r]*s1[r] + h1[r], 0.f));
      hreg[i] = pk.v;
    }
  };
  auto hwriteN = [&](int slot) {               // SRC1: regs -> LDS
    u16* dst = &hB[slot * HSTR];
    #pragma unroll
    for (int i = 0; i < 6; i++)
      *(uint4*)&dst[hslab[i]*512 + ln*8] = hreg[i];
  };
  auto stageA = [&](int s, int b) {
    const u16* as = abase + (size_t)s * ASTR;
    u16* da = &sA[wv][b][0];
    #pragma unroll
    for (int j = 0; j < 4; j++) g2l16(as + j*512, da + j*512, ln);
  };

  f32x4 acc[2][8];
  #pragma unroll
  for (int i = 0; i < 2; i++)
    #pragma unroll
    for (int j = 0; j < 8; j++) acc[i][j] = (f32x4){0.f, 0.f, 0.f, 0.f};

  if (MODE == 0 && tid < 32) sstat[tid >> 1][tid & 1] = 0.f;

  // ---- prologue: halo planes 0,1 + A stages t=0,1; one barrier ----
  if (SRC == 0) {
    stageH(0);
    stageH(1);
  } else {
    hloadN(0); hwriteN(0);
    hloadN(1); hwriteN(1);
  }
  stageA(0, 0);                                // t=0: tap0 cc0 -> s=0
  stageA(4, 1);                                // t=1: tap1 cc0 -> s=4
  __syncthreads();

  // ---- K-loop: t = cc*9 + tap ----
  int cc = 0, tap = 0;
  #pragma unroll 1
  for (int t = 0; t < 36; t++) {
    if (SRC == 0 && (t == 10 || t == 19)) __builtin_amdgcn_s_waitcnt(WAIT_VM10);
    else if (t == 35)                     __builtin_amdgcn_s_waitcnt(WAIT_VM0);
    else                                  __builtin_amdgcn_s_waitcnt(WAIT_VM4);
    if (tap == 0 && cc > 0) {                  // t = 9,18,27
      if (SRC == 0) {
        __builtin_amdgcn_sched_barrier(0);
        __builtin_amdgcn_s_barrier();
        __builtin_amdgcn_sched_barrier(0);
        if (cc < 3) stageH(cc + 1);
      } else {
        __syncthreads();                       // drains lgkm/vm; safe overwrite
        if (cc < 3) hwriteN((cc + 1) & 1);     // plane cc+1 (loaded at tap 7)
      }
    }
    const u16* myA = &sA[wv][t & 1][0];
    const u16* hpl = &hB[(cc & 1) * HSTR];
    const int dh = tap / 3, dw = tap - dh*3;
    bf16x8 af[2][2], bf[2][8];
    #pragma unroll
    for (int sub = 0; sub < 2; sub++) {
      const int q = sub*4 + quad;
      const int swzA = (q ^ (l15 & 7)) * 8;
      #pragma unroll
      for (int mt = 0; mt < 2; mt++)
        af[sub][mt] = *(const bf16x8*)&myA[(mt*16 + l15)*64 + swzA];
      #pragma unroll
      for (int nt = 0; nt < 8; nt++) {
        const int hp = (nt + dh)*18 + l15 + dw;
        bf[sub][nt] = *(const bf16x8*)&hpl[hp*64 + ((q ^ (hp & 7)) << 3)];
      }
    }
    __builtin_amdgcn_s_waitcnt(WAIT_LGKM0);
    if (SRC == 1 && tap == 7 && cc < 2) hloadN(cc + 2);  // regs; drained by use
    if (t < 34) {
      int tap2 = tap + 2, cc2 = cc;
      if (tap2 >= 9) { tap2 -= 9; cc2++; }
      stageA(tap2*4 + cc2, t & 1);
    }
    #pragma unroll
    for (int sub = 0; sub < 2; sub++)
      #pragma unroll
      for (int mt = 0; mt < 2; mt++)
        #pragma unroll
        for (int nt = 0; nt < 8; nt++)
          acc[mt][nt] = __builtin_amdgcn_mfma_f32_16x16x32_bf16(
              af[sub][mt], bf[sub][nt], acc[mt][nt], 0, 0, 0);
    if (++tap == 9) { tap = 0; cc++; }
  }

  const int gx = tx0 + l15;
  if (MODE == 0) {
    const float* __restrict__ bias = br ? bb : bc;
    float* __restrict__ Y = br ? Yb : Yc;
    #pragma unroll
    for (int mt = 0; mt < 2; mt++) {
      const int mloc = wv*32 + mt*16 + quad*4;
      const int mrow = mtile*128 + mloc;
      const f32x4 bv = *(const f32x4*)&bias[mrow];
      float s = 0.f, sq = 0.f;
      #pragma unroll
      for (int nt = 0; nt < 8; nt++) {
        const int gy = ty0 + nt;
        f32x4 v = acc[mt][nt] + bv;
        if (gy < W && gx < W) {
          const size_t n = (size_t)(c_off[lv] + gy*W + gx);
          *(f32x4*)&Y[n*CCH + mrow] = v;
          #pragma unroll
          for (int r = 0; r < 4; r++) { s += v[r]; sq += v[r]*v[r]; }
        }
      }
      #pragma unroll
      for (int o = 1; o < 16; o <<= 1) { s += __shfl_xor(s, o); sq += __shfl_xor(sq, o); }
      if (l15 == 0) {
        const int g = mloc >> 3;               // local 8-ch GN group 0..15
        atomicAdd(&sstat[g][0], s);
        atomicAdd(&sstat[g][1], sq);
      }
    }
    __syncthreads();
    if (tid < 32) {
      const int g = tid >> 1, c = tid & 1;
      atomicAdd(&stats[((br*NLEV + lv)*32 + mtile*16 + g)*2 + c], sstat[g][c]);
    }
  } else {
    const float scl = scales[lv];
    const float stf = c_stridef[lv];
    #pragma unroll
    for (int mt = 0; mt < 2; mt++) {
      const int mr0 = wv*32 + mt*16 + quad*4;
      if (mr0 >= 85) continue;
      #pragma unroll
      for (int nt = 0; nt < 8; nt++) {
        const int gy = ty0 + nt;
        if (gy >= W || gx >= W) continue;
        const size_t n = (size_t)(c_off[lv] + gy*W + gx);
        const f32x4 v = acc[mt][nt];
        #pragma unroll
        for (int r = 0; r < 4; r++) {
          const int m = mr0 + r;
          if (br == 0) {
            if (m < 80) out[n*85 + m] = v[r] + bc[m];          // logits
          } else {
            if (m < 4) {
              const float t2 = (v[r] + predb[m]) * scl;        // Scale module
              out[n*85 + 80 + m] = fmaxf(t2, 0.f) * stf;       // relu * stride
            } else if (m == 4) {
              out[n*85 + 84] = v[r] + ioub[0];                 // iou
            }
          }
        }
      }
    }
  }
}

// Fold GN stats + affine into per-channel (scale, shift):
// scale = rstd*gw ; shift = gb - mean*scale.  2*5*256 threads.
__global__ __launch_bounds__(256) void gn_coef(
    const float* __restrict__ ST, const float* __restrict__ gwc,
    const float* __restrict__ gbc, const float* __restrict__ gwb,
    const float* __restrict__ gbb,
    float* __restrict__ CFS, float* __restrict__ CFH)
{
  const int t = blockIdx.x * 256 + threadIdx.x;
  if (t >= 2*NLEV*256) return;
  const int br = t / (NLEV*256);
  const int r  = t - br*(NLEV*256);
  const int lv = r >> 8, c = r & 255, g = c >> 3;
  const float* st = &ST[((br*NLEV + lv)*32 + g)*2];
  const float cnt = 8.f * (float)c_HW[lv];
  const float mean = st[0] / cnt;
  const float var  = st[1] / cnt - mean*mean;
  const float rstd = rsqrtf(var + 1e-5f);
  const float* gw = br ? gwb : gwc;
  const float* gb = br ? gbb : gbc;
  const float s = rstd * gw[c];
  CFS[t] = s;
  CFH[t] = gb[c] - mean*s;
}

// fp32 NCHW feats -> bf16 planar padded (layer-0 input)
__global__ __launch_bounds__(256) void feat2bf(
    const float* __restrict__ p3, const float* __restrict__ p4,
    const float* __restrict__ p5, const float* __restrict__ p6,
    const float* __restrict__ p7, u16* __restrict__ X)
{
  const int t = blockIdx.x * 256 + threadIdx.x;
  if (t >= P_TOT * 32) return;
  const int pg = t >> 5, c0 = (t & 31) << 3;
  int lv = 0;
  #pragma unroll
  for (int i = 1; i < NLEV; i++) if (pg >= c_off[i]) lv = i;
  const int pl = pg - c_off[lv];
  const float* src = lv==0 ? p3 : lv==1 ? p4 : lv==2 ? p5 : lv==3 ? p6 : p7;
  const int HW = c_HW[lv], Wl = c_W[lv];
  const int h = pl / Wl, wi = pl - h*Wl;
  const size_t pidx = (size_t)(c_poff[lv] + (h+1)*(Wl+2) + (wi+1));
  union { u16 u[8]; uint4 v; } pk;
  #pragma unroll
  for (int i = 0; i < 8; i++)
    pk.u[i] = f2bf(src[(size_t)(c0+i)*HW + pl]);
  *(uint4*)&X[(size_t)(c0 >> 6)*PLS + pidx*64 + (c0 & 63)] = pk.v;
}

// tower weights [l][co][ci][9] fp32 -> PACKED stage-major swizzled bf16 (R11)
__global__ __launch_bounds__(256) void wconv(
    const float* __restrict__ cw, const float* __restrict__ bw,
    u16* __restrict__ Wc, u16* __restrict__ Wb)
{
  const size_t N = (size_t)4*256*KTOT;
  const size_t t = (size_t)blockIdx.x * 256 + threadIdx.x;
  if (t >= 2*N) return;
  const float* src = (t < N) ? cw : bw;
  u16* dst = (t < N) ? Wc : Wb;
  const size_t i = (t < N) ? t : t - N;
  const size_t lc = i / KTOT;
  const int kk = (int)(i - lc*KTOT);
  const int l = (int)(lc >> 8), co = (int)(lc & 255);
  const int tap = kk >> 8, ci = kk & 255;
  const int s = kk >> 6, kl = kk & 63;
  const int r = co & 7, p = (kl >> 3) ^ r;
  const size_t d = (size_t)l*589824 +
      ((size_t)((s*32 + (co >> 3))*64 + r*8 + p))*8 + (kl & 7);
  dst[d] = f2bf(src[(lc*256 + ci)*9 + tap]);
}

// head weights -> packed 128-row swizzled (cls: 80 rows; box: 4 pred + 1 iou)
__global__ __launch_bounds__(256) void hconv(
    const float* __restrict__ sw, const float* __restrict__ pw,
    const float* __restrict__ iw, u16* __restrict__ Whc, u16* __restrict__ Whb)
{
  const int N = 128 * KTOT;
  const int t = blockIdx.x * 256 + threadIdx.x;
  if (t >= 2*N) return;
  const int i = (t < N) ? t : t - N;
  const int co = i / KTOT, kk = i - co*KTOT;
  const int tap = kk >> 8, ci = kk & 255;
  const int s = kk >> 6, kl = kk & 63;
  const int r = co & 7, p = (kl >> 3) ^ r;
  const size_t d = ((size_t)((s*16 + (co >> 3))*64 + r*8 + p))*8 + (kl & 7);
  float v = 0.f;
  if (t < N) {
    if (co < 80) v = sw[(co*256 + ci)*9 + tap];
    Whc[d] = f2bf(v);
  } else {
    if (co < 4)       v = pw[(co*256 + ci)*9 + tap];
    else if (co == 4) v = iw[ci*9 + tap];
    Whb[d] = f2bf(v);
  }
}

extern "C" void kernel_launch(void* const* d_in, const int* in_sizes, int n_in,
                              void* d_out, int out_size, void* d_ws, size_t ws_size,
                              hipStream_t stream)
{
  const float* p3      = (const float*)d_in[0];
  const float* p4      = (const float*)d_in[1];
  const float* p5      = (const float*)d_in[2];
  const float* p6      = (const float*)d_in[3];
  const float* p7      = (const float*)d_in[4];
  const float* cls_w   = (const float*)d_in[5];
  const float* cls_b   = (const float*)d_in[6];
  const float* cls_gw  = (const float*)d_in[7];
  const float* cls_gb  = (const float*)d_in[8];
  const float* box_w   = (const float*)d_in[9];
  const float* box_b   = (const float*)d_in[10];
  const float* box_gw  = (const float*)d_in[11];
  const float* box_gb  = (const float*)d_in[12];
  const float* score_w = (const float*)d_in[13];
  const float* score_b = (const float*)d_in[14];
  const float* pred_w  = (const float*)d_in[15];
  const float* pred_b  = (const float*)d_in[16];
  const float* iou_w   = (const float*)d_in[17];
  const float* iou_b   = (const float*)d_in[18];
  const float* scales  = (const float*)d_in[19];
  float* out = (float*)d_out;

  char* w = (char*)d_ws;
  size_t o = 0;
  auto alloc = [&](size_t b) { void* p = w + o; o += (b + 255) & ~(size_t)255; return p; };
  // XF + ST first: zeroed by ONE memset (256B multiples)
  u16*   XF = (u16*)alloc((size_t)PP_TOT*CCH*2);        // planar [4][PP_TOT][64]
  float* ST = (float*)alloc((size_t)4*2*NLEV*32*2*4);   // [layer][br][lv][32][2]
  u16*  WRC = (u16*)alloc((size_t)4*256*KTOT*2);
  u16*  WRB = (u16*)alloc((size_t)4*256*KTOT*2);
  u16*  WHC = (u16*)alloc((size_t)128*KTOT*2);
  u16*  WHB = (u16*)alloc((size_t)128*KTOT*2);
  float* YPC = (float*)alloc((size_t)P_TOT*CCH*4);      // ping
  float* YPB = (float*)alloc((size_t)P_TOT*CCH*4);
  float* YQC = (float*)alloc((size_t)P_TOT*CCH*4);      // pong
  float* YQB = (float*)alloc((size_t)P_TOT*CCH*4);
  float* CFS = (float*)alloc((size_t)4*2*NLEV*256*4);   // [layer][br][lv][256]
  float* CFH = (float*)alloc((size_t)4*2*NLEV*256*4);

  // zero padded layer-0 activation borders + all layers' GN stats
  hipMemsetAsync(XF, 0, (size_t)PP_TOT*CCH*2 + (size_t)4*2*NLEV*32*2*4, stream);

  wconv<<<dim3((unsigned)(((size_t)2*4*256*KTOT + 255)/256)), 256, 0, stream>>>(cls_w, box_w, WRC, WRB);
  hconv<<<dim3((2*128*KTOT + 255)/256), 256, 0, stream>>>(score_w, pred_w, iou_w, WHC, WHB);
  feat2bf<<<dim3((P_TOT*32 + 255)/256), 256, 0, stream>>>(p3, p4, p5, p6, p7, XF);

  const int CFN = 2*NLEV*256;
  float* YoutC[4] = {YPC, YQC, YPC, YQC};
  float* YoutB[4] = {YPB, YQB, YPB, YQB};

  // layer 0: bf16 planar input
  gemm_conv<0,0><<<dim3(74, 2, 2), 256, 0, stream>>>(
      XF, XF, nullptr, nullptr, nullptr, nullptr,
      WRC, WRB, cls_b, box_b, YoutC[0], YoutB[0], ST,
      nullptr, nullptr, nullptr, nullptr);
  gn_coef<<<dim3((CFN + 255)/256), 256, 0, stream>>>(
      ST, cls_gw, cls_gb, box_gw, box_gb, CFS, CFH);

  // layers 1..3: fp32 Y input + folded GN coefs
  for (int l = 1; l < 4; l++) {
    float* STl = ST + (size_t)l*2*NLEV*32*2;
    gemm_conv<0,1><<<dim3(74, 2, 2), 256, 0, stream>>>(
        nullptr, nullptr, YoutC[l-1], YoutB[l-1],
        CFS + (size_t)(l-1)*CFN, CFH + (size_t)(l-1)*CFN,
        WRC + (size_t)l*589824, WRB + (size_t)l*589824,
        cls_b + l*256, box_b + l*256, YoutC[l], YoutB[l], STl,
        nullptr, nullptr, nullptr, nullptr);
    gn_coef<<<dim3((CFN + 255)/256), 256, 0, stream>>>(
        STl, cls_gw + l*256, cls_gb + l*256, box_gw + l*256, box_gb + l*256,
        CFS + (size_t)l*CFN, CFH + (size_t)l*CFN);
  }

  // heads: normalize layer-3 Y on the fly
  gemm_conv<1,1><<<dim3(74, 1, 2), 256, 0, stream>>>(
      nullptr, nullptr, YoutC[3], YoutB[3],
      CFS + (size_t)3*CFN, CFH + (size_t)3*CFN,
      WHC, WHB, score_b, nullptr, nullptr, nullptr, nullptr,
      pred_b, iou_b, scales, out);
}